// Round 1
// 5375.002 us; speedup vs baseline: 1.0454x; 1.0454x over previous
//
#include <hip/hip_runtime.h>
#include <cstdint>

// RNNLM: embed-gather(shift) -> [LSTM x2, fused+pipelined] -> logits GEMM.
// bf16 MFMA everywhere, fp32 gate math. Both LSTM layers fused in ONE
// persistent kernel of 32 WGs: each WG owns a 64-gate-col slice of layer 0
// (step f) AND of layer 1 (step f-1). Single uniform flag condition per
// round (all flags >= f), one release store per WG per round. h0 fragments
// are loaded once and reused for both the Wh0 (L0) and Wx1 (L1) MFMAs.
// Weights register-resident (192 regs/wave). Poll traffic: 32 lanes x 128
// waves (4x less than the previous 64-WG two-chain design).

typedef float    f32x4  __attribute__((ext_vector_type(4)));
typedef __bf16   bf16x8 __attribute__((ext_vector_type(8)));
typedef uint16_t u16;

constexpr int BB = 8, T = 512, D = 512, V = 32000;
constexpr int M4 = BB * T;   // 4096 rows (b*T+t)
constexpr int G  = 4 * D;    // 2048 gates
constexpr int FS = 16;       // flag stride in ints (64 B padding)

static __device__ __forceinline__ u16 f2bf(float f) {
  union { float f; uint32_t u; } v{f};
  uint32_t r = v.u + 0x7fffu + ((v.u >> 16) & 1u);   // RNE
  return (u16)(r >> 16);
}
static __device__ __forceinline__ float sigm(float x)  { return 1.f / (1.f + __expf(-x)); }
static __device__ __forceinline__ float tanhr(float x) { return 1.f - 2.f / (__expf(2.f * x) + 1.f); }

// ---------------- embed gather with ShiftRight, f32 -> bf16 ----------------
__global__ void embed_kernel(const int* __restrict__ tok, const float* __restrict__ emb,
                             u16* __restrict__ Xbf) {
  int m = blockIdx.x;                 // m = b*T + t
  int b = m >> 9, t = m & 511;
  int id = t ? tok[b * T + t - 1] : 0;
  const float* src = emb + (size_t)id * D;
  u16* dst = Xbf + (size_t)m * D;
  for (int d = threadIdx.x; d < D; d += 256) dst[d] = f2bf(src[d]);
}

// ------------- transpose f32[512][Cn] -> bf16[Cn][512], optional gate-interleave -------------
template <bool PERM>
__global__ void transpose_cast(const float* __restrict__ src, u16* __restrict__ dst, int Cn) {
  __shared__ float tl[64][65];
  int n0 = blockIdx.x * 64, k0 = blockIdx.y * 64;
  int tx = threadIdx.x & 63, ty = threadIdx.x >> 6;
  for (int r = ty; r < 64; r += 4) tl[r][tx] = src[(size_t)(k0 + r) * Cn + n0 + tx];
  __syncthreads();
  for (int r = ty; r < 64; r += 4) {
    int n = n0 + r;
    int q = PERM ? ((n & (D - 1)) * 4 + (n >> 9)) : n;
    dst[(size_t)q * D + k0 + tx] = f2bf(tl[tx][r]);
  }
}

__global__ void bias_perm(const float* __restrict__ b, float* __restrict__ bp) {
  int q = blockIdx.x * 256 + threadIdx.x;
  if (q < G) bp[q] = b[(q & 3) * D + (q >> 2)];
}

// ---------------- m97-style bf16 GEMM: C[M,N] = A[M,K] @ BT[N,K]^T + bias ----------------
__global__ __launch_bounds__(256) void gemm_bt(
    const u16* __restrict__ A, const u16* __restrict__ BT,
    const float* __restrict__ bias, float* __restrict__ C, int N, int K) {
  __shared__ u16 As[128 * 32], Bs[128 * 32];
  const int lane = threadIdx.x & 63, wave = threadIdx.x >> 6;
  const int m0 = blockIdx.y * 128, n0 = blockIdx.x * 128;
  const int wm = (wave >> 1) * 64, wn = (wave & 1) * 64;
  const int lr = lane >> 2, lc = (lane & 3) * 8;
  f32x4 acc[4][4] = {};
  for (int kk = 0; kk < K; kk += 32) {
#pragma unroll
    for (int i = 0; i < 2; ++i) {
      int row = wave * 32 + i * 16;
      __builtin_amdgcn_global_load_lds(
          (const __attribute__((address_space(1))) uint32_t*)(A + (size_t)(m0 + row + lr) * K + kk + lc),
          (__attribute__((address_space(3))) uint32_t*)(As + row * 32), 16, 0, 0);
      __builtin_amdgcn_global_load_lds(
          (const __attribute__((address_space(1))) uint32_t*)(BT + (size_t)(n0 + row + lr) * K + kk + lc),
          (__attribute__((address_space(3))) uint32_t*)(Bs + row * 32), 16, 0, 0);
    }
    __syncthreads();
    bf16x8 af[4], bf[4];
#pragma unroll
    for (int i = 0; i < 4; ++i) {
      af[i] = *(const bf16x8*)(As + (wm + i * 16 + (lane & 15)) * 32 + (lane >> 4) * 8);
      bf[i] = *(const bf16x8*)(Bs + (wn + i * 16 + (lane & 15)) * 32 + (lane >> 4) * 8);
    }
#pragma unroll
    for (int mi = 0; mi < 4; ++mi)
#pragma unroll
      for (int ni = 0; ni < 4; ++ni)
        acc[mi][ni] = __builtin_amdgcn_mfma_f32_16x16x32_bf16(af[mi], bf[ni], acc[mi][ni], 0, 0, 0);
    __syncthreads();
  }
  const int cr = (lane >> 4) * 4, cc = lane & 15;
#pragma unroll
  for (int ni = 0; ni < 4; ++ni) {
    int col = n0 + wn + ni * 16 + cc;
    float bv = bias[col];
#pragma unroll
    for (int mi = 0; mi < 4; ++mi) {
      size_t base = (size_t)(m0 + wm + mi * 16 + cr) * N + col;
#pragma unroll
      for (int r = 0; r < 4; ++r) C[base + (size_t)r * N] = acc[mi][ni][r] + bv;
    }
  }
}

// ---------------- fused 2-layer pipelined LSTM scan (combined WGs) ----------------
// 32 WGs x 256 threads. Round f (f in [0,T]):
//   L0 step t=f   (f<T):  gates = h0[f-1] @ Wh0  + xw0[f]
//   L1 step t=f-1 (f>=1): gates = h0[f-1] @ Wx1  + h1[f-2] @ Wh1 + b1
// Single condition per round: all 32 flags >= f (flag=f published after
// round f-1 completed all its ring writes). h0 frags shared by L0 and L1.
// Rings: H0ring/H1ring bf16 [2][16][512] (rows 8..15 zero-padding).
__global__ __launch_bounds__(256, 1) void lstm_fused(
    const u16* __restrict__ WhT0, const u16* __restrict__ WhT1, const u16* __restrict__ WxT1,
    const float* __restrict__ xw0, const float* __restrict__ b1p,
    u16* __restrict__ H0ring, u16* __restrict__ H1ring, u16* __restrict__ Hseq1,
    int* __restrict__ flags) {
  __shared__ float Cst[4][16][16];     // per-wave slice: C^T scratch (intra-wave only)
  const int tid = threadIdx.x, lane = tid & 63, wave = tid >> 6, wg = blockIdx.x;
  const int wvg = wg * 4 + wave;             // global wave 0..127
  const int q16 = wvg * 16;                  // this wave's 16 gate columns (q = 4d+tau)
  const int fr = lane & 15, quad = lane >> 4;
  const bool gl = lane < 32;
  const int b = lane & 7, dl = (lane >> 3) & 3;
  const int dbase = wvg * 4;                 // wave's 4 d-dims

  // register-resident weights: Wh0, Wh1, Wx1 fragments (16 cols x 512 K each)
  bf16x8 whf0[16], whf1[16], wxf1[16];
#pragma unroll
  for (int kb = 0; kb < 16; ++kb) {
    whf0[kb] = *(const bf16x8*)(WhT0 + (size_t)(q16 + fr) * 512 + kb * 32 + quad * 8);
    whf1[kb] = *(const bf16x8*)(WhT1 + (size_t)(q16 + fr) * 512 + kb * 32 + quad * 8);
    wxf1[kb] = *(const bf16x8*)(WxT1 + (size_t)(q16 + fr) * 512 + kb * 32 + quad * 8);
  }
  float4 bias4 = *(const float4*)(b1p + q16 + dl * 4);

  float c0 = 0.f, c1 = 0.f;
  for (int f = 0; f <= T; ++f) {
    const bool doL0 = (f < T), doL1 = (f >= 1);
    // prefetch xw0 slice for L0 gating (independent of flags -> hides latency)
    float4 x4;
    if (doL0 && gl) x4 = *(const float4*)(xw0 + (size_t)(b * T + f) * G + q16 + dl * 4);
    // ---- poll: all WGs finished round f-1 ----
    for (;;) {
      int v = f;
      if (lane < 32) v = __hip_atomic_load(&flags[lane * FS], __ATOMIC_ACQUIRE, __HIP_MEMORY_SCOPE_AGENT);
      if (__all(v >= f)) break;
      __builtin_amdgcn_s_sleep(1);
    }
    const u16* h0p = H0ring + ((f & 1) ^ 1) * 8192;   // h0[f-1]
    const u16* h1p = H1ring + (f & 1) * 8192;         // h1[f-2]
    f32x4 acA0 = {}, acA1 = {}, acB0 = {}, acB1 = {};
#pragma unroll
    for (int kb = 0; kb < 16; kb += 2) {
      bf16x8 a0 = *(const bf16x8*)(h0p + fr * 512 + kb * 32 + quad * 8);
      bf16x8 a1 = *(const bf16x8*)(h0p + fr * 512 + (kb + 1) * 32 + quad * 8);
      if (doL0) {
        acA0 = __builtin_amdgcn_mfma_f32_16x16x32_bf16(a0, whf0[kb], acA0, 0, 0, 0);
        acA1 = __builtin_amdgcn_mfma_f32_16x16x32_bf16(a1, whf0[kb + 1], acA1, 0, 0, 0);
      }
      if (doL1) {
        acB0 = __builtin_amdgcn_mfma_f32_16x16x32_bf16(a0, wxf1[kb], acB0, 0, 0, 0);
        acB1 = __builtin_amdgcn_mfma_f32_16x16x32_bf16(a1, wxf1[kb + 1], acB1, 0, 0, 0);
        bf16x8 b0v = *(const bf16x8*)(h1p + fr * 512 + kb * 32 + quad * 8);
        bf16x8 b1v = *(const bf16x8*)(h1p + fr * 512 + (kb + 1) * 32 + quad * 8);
        acB0 = __builtin_amdgcn_mfma_f32_16x16x32_bf16(b0v, whf1[kb], acB0, 0, 0, 0);
        acB1 = __builtin_amdgcn_mfma_f32_16x16x32_bf16(b1v, whf1[kb + 1], acB1, 0, 0, 0);
      }
    }
    // ---- L0 gating: h0[f] ----
    if (doL0) {
      f32x4 acc = acA0 + acA1;
#pragma unroll
      for (int r = 0; r < 4; ++r) Cst[wave][quad * 4 + r][fr] = acc[r];
      if (gl) {
        float pi = Cst[wave][b][dl * 4 + 0] + x4.x;
        float pf = Cst[wave][b][dl * 4 + 1] + x4.y;
        float pg = Cst[wave][b][dl * 4 + 2] + x4.z;
        float po = Cst[wave][b][dl * 4 + 3] + x4.w;
        float ig = sigm(pi), fg = sigm(pf), gg = tanhr(pg), og = sigm(po);
        c0 = fg * c0 + ig * gg;
        int hv = f2bf(og * tanhr(c0));
        int g0 = __shfl(hv, b + 0), g1 = __shfl(hv, b + 8);
        int g2 = __shfl(hv, b + 16), g3 = __shfl(hv, b + 24);
        if (lane < 8) {
          ushort4 pk = { (u16)g0, (u16)g1, (u16)g2, (u16)g3 };
          *(ushort4*)(H0ring + (f & 1) * 8192 + b * 512 + dbase) = pk;
        }
      }
    }
    // ---- L1 gating: h1[f-1] ----
    ushort4 p; bool st1 = false;
    if (doL1) {
      f32x4 acc = acB0 + acB1;
#pragma unroll
      for (int r = 0; r < 4; ++r) Cst[wave][quad * 4 + r][fr] = acc[r];
      if (gl) {
        float pi = Cst[wave][b][dl * 4 + 0] + bias4.x;
        float pf = Cst[wave][b][dl * 4 + 1] + bias4.y;
        float pg = Cst[wave][b][dl * 4 + 2] + bias4.z;
        float po = Cst[wave][b][dl * 4 + 3] + bias4.w;
        float ig = sigm(pi), fg = sigm(pf), gg = tanhr(pg), og = sigm(po);
        c1 = fg * c1 + ig * gg;
        int hv = f2bf(og * tanhr(c1));
        int g0 = __shfl(hv, b + 0), g1 = __shfl(hv, b + 8);
        int g2 = __shfl(hv, b + 16), g3 = __shfl(hv, b + 24);
        p = { (u16)g0, (u16)g1, (u16)g2, (u16)g3 };
        if (lane < 8) {
          st1 = true;
          *(ushort4*)(H1ring + ((f - 1) & 1) * 8192 + b * 512 + dbase) = p;
        }
      }
    }
    __syncthreads();   // per-wave vmcnt(0): all 4 waves' ring stores drained
    if (tid == 0)
      __hip_atomic_store(&flags[wg * FS], f + 1, __ATOMIC_RELEASE, __HIP_MEMORY_SCOPE_AGENT);
    if (st1)           // off critical path: consumed by logits GEMM at kernel end
      *(ushort4*)(Hseq1 + (size_t)(b * T + (f - 1)) * 512 + dbase) = p;
  }
}

extern "C" void kernel_launch(void* const* d_in, const int* in_sizes, int n_in,
                              void* d_out, int out_size, void* d_ws, size_t ws_size,
                              hipStream_t stream) {
  (void)in_sizes; (void)n_in; (void)out_size; (void)ws_size;
  const int*   tokens = (const int*)d_in[0];
  const float* embed  = (const float*)d_in[1];
  const float* Wx0 = (const float*)d_in[2];
  const float* Wh0 = (const float*)d_in[3];
  const float* b0  = (const float*)d_in[4];
  const float* Wx1 = (const float*)d_in[5];
  const float* Wh1 = (const float*)d_in[6];
  const float* b1  = (const float*)d_in[7];
  const float* Wout = (const float*)d_in[8];
  const float* bout = (const float*)d_in[9];

  char* ws = (char*)d_ws;
  size_t off = 0;
  auto alloc = [&](size_t bytes) -> char* {
    char* p = ws + off; off += (bytes + 255) & ~(size_t)255; return p;
  };
  float* xw  = (float*)alloc((size_t)M4 * G * 4);  // 32 MB; WoutT aliases after scan
  u16* WoutT = (u16*)xw;
  u16* Xbf   = (u16*)alloc((size_t)M4 * D * 2);
  u16* WxT0  = (u16*)alloc((size_t)G * D * 2);
  u16* WhT0  = (u16*)alloc((size_t)G * D * 2);
  u16* WxT1  = (u16*)alloc((size_t)G * D * 2);
  u16* WhT1  = (u16*)alloc((size_t)G * D * 2);
  u16* Hseq1 = (u16*)alloc((size_t)M4 * D * 2);
  float* b0p = (float*)alloc(G * 4);
  float* b1p = (float*)alloc(G * 4);
  char* zbase = ws + off;                           // zero-init region
  u16* H0ring = (u16*)alloc(2 * 16 * 512 * 2);
  u16* H1ring = (u16*)alloc(2 * 16 * 512 * 2);
  int* flags  = (int*)alloc(64 * FS * 4);
  size_t zbytes = (size_t)((ws + off) - zbase);
  hipMemsetAsync(zbase, 0, zbytes, stream);

  embed_kernel<<<M4, 256, 0, stream>>>(tokens, embed, Xbf);
  transpose_cast<true ><<<dim3(G / 64, 8), 256, 0, stream>>>(Wx0, WxT0, G);
  transpose_cast<true ><<<dim3(G / 64, 8), 256, 0, stream>>>(Wh0, WhT0, G);
  transpose_cast<true ><<<dim3(G / 64, 8), 256, 0, stream>>>(Wx1, WxT1, G);
  transpose_cast<true ><<<dim3(G / 64, 8), 256, 0, stream>>>(Wh1, WhT1, G);
  bias_perm<<<G / 256, 256, 0, stream>>>(b0, b0p);
  bias_perm<<<G / 256, 256, 0, stream>>>(b1, b1p);

  gemm_bt<<<dim3(G / 128, M4 / 128), 256, 0, stream>>>(Xbf, WxT0, b0p, xw, G, D);
  lstm_fused<<<32, 256, 0, stream>>>(WhT0, WhT1, WxT1, xw, b1p, H0ring, H1ring, Hseq1, flags);
  transpose_cast<false><<<dim3(V / 64, 8), 256, 0, stream>>>(Wout, WoutT, V);
  gemm_bt<<<dim3(V / 128, M4 / 128), 256, 0, stream>>>(Hseq1, WoutT, bout, (float*)d_out, V, D);
}